// Round 1
// baseline (392.912 us; speedup 1.0000x reference)
//
#include <hip/hip_runtime.h>
#include <math.h>

#define H 768
#define S 256
#define NB 4      // batch
#define TOPK 4
#define L 4

// tanh(x) = (e^{2x}-1)/(e^{2x}+1); clamp so exp never overflows (tanh(15)==1.0f in fp32)
__device__ __forceinline__ float fast_tanh(float x) {
  float cx = fminf(15.f, fmaxf(-15.f, x));
  float e = __expf(cx + cx);
  return __fdividef(e - 1.f, e + 1.f);
}

// ---------------------------------------------------------------------------
// Stage 1: hij[row][0:768] = pooled @ Wa^T + Wa_b ; hij[row][768:1536] = pooled @ Ua^T + Ua_b
// C[row,n] = sum_h A[row,h] * W[n,h]  (both row-major, dot over h)
// 64x64 tile, BK=32, 256 threads, 4x4 micro-tile.
__global__ __launch_bounds__(256) void proj_kernel(
    const float* __restrict__ pooled, const float* __restrict__ Wa_w,
    const float* __restrict__ Wa_b, const float* __restrict__ Ua_w,
    const float* __restrict__ Ua_b, float* __restrict__ hij) {
  __shared__ float as[32][68];  // [k][m], stride 68: 16B aligned rows, benign banking
  __shared__ float bs[32][68];  // [k][n]
  const int m0 = blockIdx.x * 64;
  const int nblk = blockIdx.y;             // 0..23 (0..11 -> Wa, 12..23 -> Ua)
  const bool isUa = nblk >= 12;
  const float* Wm = isUa ? Ua_w : Wa_w;
  const float* bias = isUa ? Ua_b : Wa_b;
  const int n0 = (nblk - (isUa ? 12 : 0)) * 64;
  const int t = threadIdx.x;
  const int h4 = t & 7;   // k-quad
  const int rl = t >> 3;  // 0..31
  const int mm = (t & 15) * 4;
  const int nn = (t >> 4) * 4;
  float acc[4][4] = {};

  for (int kc = 0; kc < H; kc += 32) {
#pragma unroll
    for (int p = 0; p < 2; ++p) {
      int row = rl + p * 32;
      float4 v = *(const float4*)&pooled[(m0 + row) * H + kc + h4 * 4];
      as[h4 * 4 + 0][row] = v.x; as[h4 * 4 + 1][row] = v.y;
      as[h4 * 4 + 2][row] = v.z; as[h4 * 4 + 3][row] = v.w;
      float4 w = *(const float4*)&Wm[(n0 + row) * H + kc + h4 * 4];
      bs[h4 * 4 + 0][row] = w.x; bs[h4 * 4 + 1][row] = w.y;
      bs[h4 * 4 + 2][row] = w.z; bs[h4 * 4 + 3][row] = w.w;
    }
    __syncthreads();
#pragma unroll
    for (int k = 0; k < 32; ++k) {
      float4 a4 = *(const float4*)&as[k][mm];
      float4 b4 = *(const float4*)&bs[k][nn];
      float av[4] = {a4.x, a4.y, a4.z, a4.w};
      float bv[4] = {b4.x, b4.y, b4.z, b4.w};
#pragma unroll
      for (int i = 0; i < 4; ++i)
#pragma unroll
        for (int j = 0; j < 4; ++j) acc[i][j] = fmaf(av[i], bv[j], acc[i][j]);
    }
    __syncthreads();
  }
  const int ncol0 = nblk * 64;
#pragma unroll
  for (int i = 0; i < 4; ++i) {
    float4 o;
    o.x = acc[i][0] + bias[n0 + nn + 0];
    o.y = acc[i][1] + bias[n0 + nn + 1];
    o.z = acc[i][2] + bias[n0 + nn + 2];
    o.w = acc[i][3] + bias[n0 + nn + 3];
    *(float4*)&hij[(m0 + mm + i) * 1536 + ncol0 + nn] = o;
  }
}

// ---------------------------------------------------------------------------
// Stage 2: logits[b,a,c] = sum_h va[h] * tanh(hi[b,c,h] + hj[b,a,h])
// 16x16 (a,c) tile per block, 256 threads = 1 pair each, h chunked by 64.
__global__ __launch_bounds__(256) void biaffine_kernel(
    const float* __restrict__ hij, const float* __restrict__ va,
    float* __restrict__ logits) {
  __shared__ float his[16][68];  // [c][h]
  __shared__ float hjs[16][68];  // [a][h]
  __shared__ float vas[H];
  const int b = blockIdx.z;
  const int a0 = blockIdx.y * 16;
  const int c0 = blockIdx.x * 16;
  const int t = threadIdx.x;
  for (int i = t; i < H; i += 256) vas[i] = va[i];
  const int tx = t & 15;       // c
  const int ty = t >> 4;       // a
  const int hload = t & 63;
  const int rbase = t >> 6;    // 0..3
  float acc = 0.f;

  for (int hc = 0; hc < H; hc += 64) {
#pragma unroll
    for (int i = 0; i < 4; ++i) {
      int row = rbase + 4 * i;
      his[row][hload] = hij[(b * S + c0 + row) * 1536 + hc + hload];
      hjs[row][hload] = hij[(b * S + a0 + row) * 1536 + 768 + hc + hload];
    }
    __syncthreads();
#pragma unroll
    for (int h = 0; h < 64; h += 4) {
      float4 xi = *(const float4*)&his[tx][h];
      float4 xj = *(const float4*)&hjs[ty][h];
      float4 vv = *(const float4*)&vas[hc + h];
      acc = fmaf(vv.x, fast_tanh(xi.x + xj.x), acc);
      acc = fmaf(vv.y, fast_tanh(xi.y + xj.y), acc);
      acc = fmaf(vv.z, fast_tanh(xi.z + xj.z), acc);
      acc = fmaf(vv.w, fast_tanh(xi.w + xj.w), acc);
    }
    __syncthreads();
  }
  logits[(b * S + a0 + ty) * S + c0 + tx] = acc;
}

// ---------------------------------------------------------------------------
// Stage 3: top-4 over c for each (b,a) row; tie-break = smaller index (jax.lax.top_k).
__global__ __launch_bounds__(64) void topk_kernel(
    const float* __restrict__ logits, int* __restrict__ idx) {
  const int row = blockIdx.x;  // b*S + a
  const int lane = threadIdx.x;
  float v[4];
#pragma unroll
  for (int j = 0; j < 4; ++j) v[j] = logits[row * S + j * 64 + lane];
#pragma unroll
  for (int k = 0; k < TOPK; ++k) {
    float bestv = v[0];
    int besti = lane;
#pragma unroll
    for (int j = 1; j < 4; ++j) {
      int c = j * 64 + lane;
      if (v[j] > bestv) { bestv = v[j]; besti = c; }  // strict >: keeps smaller c on tie
    }
#pragma unroll
    for (int off = 32; off > 0; off >>= 1) {
      float ov = __shfl_xor(bestv, off);
      int oi = __shfl_xor(besti, off);
      if (ov > bestv || (ov == bestv && oi < besti)) { bestv = ov; besti = oi; }
    }
    int mj = besti >> 6, ml = besti & 63;
#pragma unroll
    for (int j = 0; j < 4; ++j)
      if (lane == ml && j == mj) v[j] = -3.402823466e38f;
    if (lane == 0) idx[row * TOPK + k] = besti;
  }
}

// ---------------------------------------------------------------------------
// Stage 4: hidden[r,o] = tanh( cat[r,:] . dense_w[o,:] + dense_b[o] ), r over 4096 rows
// cat[r, 0:768] = pooled[b,s], cat[r, 768:1536] = pooled[b, idx[b,s,k]]
__global__ __launch_bounds__(256) void dense_kernel(
    const float* __restrict__ pooled, const int* __restrict__ idx,
    const float* __restrict__ dense_w, const float* __restrict__ dense_b,
    float* __restrict__ hidden) {
  __shared__ float as[32][68];
  __shared__ float bs[32][68];
  const int m0 = blockIdx.x * 64;  // over 4096 rows
  const int n0 = blockIdx.y * 64;  // over 768 out channels
  const int t = threadIdx.x;
  const int h4 = t & 7;
  const int rl = t >> 3;
  const float* adep[2];
  const float* ahead[2];
#pragma unroll
  for (int p = 0; p < 2; ++p) {
    int r = m0 + rl + p * 32;
    int k = r & 3, s = (r >> 2) & 255, b = r >> 10;
    adep[p] = pooled + (b * S + s) * H;
    int hid = idx[(b * S + s) * TOPK + k];
    ahead[p] = pooled + (b * S + hid) * H;
  }
  const int mm = (t & 15) * 4;
  const int nn = (t >> 4) * 4;
  float acc[4][4] = {};

  for (int kc = 0; kc < 2 * H; kc += 32) {
    const int ko = (kc < H) ? kc : kc - H;
    const bool dep = (kc < H);
#pragma unroll
    for (int p = 0; p < 2; ++p) {
      int row = rl + p * 32;
      const float* ap = dep ? adep[p] : ahead[p];
      float4 v = *(const float4*)&ap[ko + h4 * 4];
      as[h4 * 4 + 0][row] = v.x; as[h4 * 4 + 1][row] = v.y;
      as[h4 * 4 + 2][row] = v.z; as[h4 * 4 + 3][row] = v.w;
      float4 w = *(const float4*)&dense_w[(n0 + row) * (2 * H) + kc + h4 * 4];
      bs[h4 * 4 + 0][row] = w.x; bs[h4 * 4 + 1][row] = w.y;
      bs[h4 * 4 + 2][row] = w.z; bs[h4 * 4 + 3][row] = w.w;
    }
    __syncthreads();
#pragma unroll
    for (int k = 0; k < 32; ++k) {
      float4 a4 = *(const float4*)&as[k][mm];
      float4 b4 = *(const float4*)&bs[k][nn];
      float av[4] = {a4.x, a4.y, a4.z, a4.w};
      float bv[4] = {b4.x, b4.y, b4.z, b4.w};
#pragma unroll
      for (int i = 0; i < 4; ++i)
#pragma unroll
        for (int j = 0; j < 4; ++j) acc[i][j] = fmaf(av[i], bv[j], acc[i][j]);
    }
    __syncthreads();
  }
#pragma unroll
  for (int i = 0; i < 4; ++i) {
    float4 o;
    o.x = fast_tanh(acc[i][0] + dense_b[n0 + nn + 0]);
    o.y = fast_tanh(acc[i][1] + dense_b[n0 + nn + 1]);
    o.z = fast_tanh(acc[i][2] + dense_b[n0 + nn + 2]);
    o.w = fast_tanh(acc[i][3] + dense_b[n0 + nn + 3]);
    *(float4*)&hidden[(m0 + mm + i) * H + n0 + nn] = o;
  }
}

// ---------------------------------------------------------------------------
// Stage 5: type_logits[r,l] = hidden[r,:] . fc_w[l,:] + fc_b[l]
__global__ __launch_bounds__(64) void fc_kernel(
    const float* __restrict__ hidden, const float* __restrict__ fc_w,
    const float* __restrict__ fc_b, float* __restrict__ out_type) {
  const int r = blockIdx.x;
  const int lane = threadIdx.x;
  float acc[L] = {};
#pragma unroll
  for (int j = 0; j < H / 64; ++j) {
    int h = j * 64 + lane;
    float x = hidden[r * H + h];
#pragma unroll
    for (int l = 0; l < L; ++l) acc[l] = fmaf(x, fc_w[l * H + h], acc[l]);
  }
#pragma unroll
  for (int l = 0; l < L; ++l)
#pragma unroll
    for (int off = 32; off > 0; off >>= 1) acc[l] += __shfl_xor(acc[l], off);
  if (lane == 0) {
#pragma unroll
    for (int l = 0; l < L; ++l) out_type[r * L + l] = acc[l] + fc_b[l];
  }
}

// ---------------------------------------------------------------------------
extern "C" void kernel_launch(void* const* d_in, const int* in_sizes, int n_in,
                              void* d_out, int out_size, void* d_ws, size_t ws_size,
                              hipStream_t stream) {
  const float* pooled  = (const float*)d_in[0];
  const float* Wa_w    = (const float*)d_in[1];
  const float* Wa_b    = (const float*)d_in[2];
  const float* Ua_w    = (const float*)d_in[3];
  const float* Ua_b    = (const float*)d_in[4];
  const float* va_w    = (const float*)d_in[5];
  const float* dense_w = (const float*)d_in[6];
  const float* dense_b = (const float*)d_in[7];
  const float* fc_w    = (const float*)d_in[8];
  const float* fc_b    = (const float*)d_in[9];

  float* logits   = (float*)d_out;            // (4,256,256) = 262144
  float* out_type = logits + NB * S * S;      // (4,256,4,4) = 16384

  float* hij    = (float*)d_ws;               // 1024 x 1536 fp32 = 6 MB
  int*   idxbuf = (int*)(hij + 1024 * 1536);  // 4096 ints
  float* hidden = (float*)(idxbuf + NB * S * TOPK);  // 4096 x 768 fp32 = 12.6 MB

  proj_kernel<<<dim3(16, 24), 256, 0, stream>>>(pooled, Wa_w, Wa_b, Ua_w, Ua_b, hij);
  biaffine_kernel<<<dim3(16, 16, 4), 256, 0, stream>>>(hij, va_w, logits);
  topk_kernel<<<dim3(1024), 64, 0, stream>>>(logits, idxbuf);
  dense_kernel<<<dim3(64, 12), 256, 0, stream>>>(pooled, idxbuf, dense_w, dense_b, hidden);
  fc_kernel<<<dim3(4096), 64, 0, stream>>>(hidden, fc_w, fc_b, out_type);
}

// Round 2
// 302.073 us; speedup vs baseline: 1.3007x; 1.3007x over previous
//
#include <hip/hip_runtime.h>
#include <math.h>

#define H 768
#define S 256
#define NB 4      // batch
#define TOPK 4
#define L 4

typedef __bf16 bf16x8 __attribute__((ext_vector_type(8)));
typedef float floatx4 __attribute__((ext_vector_type(4)));

// tanh(x) = (e^{2x}-1)/(e^{2x}+1); clamp so exp never overflows (tanh(15)==1.0f in fp32)
__device__ __forceinline__ float fast_tanh(float x) {
  float cx = fminf(15.f, fmaxf(-15.f, x));
  float e = __expf(cx + cx);
  return __fdividef(e - 1.f, e + 1.f);
}

// ---------------------------------------------------------------------------
// Stage 0: convert pooled (786432 f) and dense_w (1179648 f) to bf16
__global__ __launch_bounds__(256) void cvt_kernel(
    const float* __restrict__ a, const float* __restrict__ w,
    __bf16* __restrict__ ab, __bf16* __restrict__ wb) {
  const int NA = (NB * S * H) / 4;           // 196608 float4's in pooled
  const int NW = (H * 2 * H) / 4;            // 294912 float4's in dense_w
  int i = blockIdx.x * 256 + threadIdx.x;
  if (i >= NA + NW) return;
  float4 v;
  __bf16* o;
  if (i < NA) { v = ((const float4*)a)[i]; o = ab + i * 4; }
  else        { v = ((const float4*)w)[i - NA]; o = wb + (size_t)(i - NA) * 4; }
  union { __bf16 h[4]; ushort4 u; } tmp;
  tmp.h[0] = (__bf16)v.x; tmp.h[1] = (__bf16)v.y;
  tmp.h[2] = (__bf16)v.z; tmp.h[3] = (__bf16)v.w;
  *(ushort4*)o = tmp.u;
}

// ---------------------------------------------------------------------------
// Stage 1: hij[row][0:768] = pooled @ Wa^T + Wa_b ; hij[row][768:1536] = pooled @ Ua^T + Ua_b
__global__ __launch_bounds__(256) void proj_kernel(
    const float* __restrict__ pooled, const float* __restrict__ Wa_w,
    const float* __restrict__ Wa_b, const float* __restrict__ Ua_w,
    const float* __restrict__ Ua_b, float* __restrict__ hij) {
  __shared__ float as[32][68];
  __shared__ float bs[32][68];
  const int m0 = blockIdx.x * 64;
  const int nblk = blockIdx.y;             // 0..23 (0..11 -> Wa, 12..23 -> Ua)
  const bool isUa = nblk >= 12;
  const float* Wm = isUa ? Ua_w : Wa_w;
  const float* bias = isUa ? Ua_b : Wa_b;
  const int n0 = (nblk - (isUa ? 12 : 0)) * 64;
  const int t = threadIdx.x;
  const int h4 = t & 7;
  const int rl = t >> 3;
  const int mm = (t & 15) * 4;
  const int nn = (t >> 4) * 4;
  float acc[4][4] = {};

  for (int kc = 0; kc < H; kc += 32) {
#pragma unroll
    for (int p = 0; p < 2; ++p) {
      int row = rl + p * 32;
      float4 v = *(const float4*)&pooled[(m0 + row) * H + kc + h4 * 4];
      as[h4 * 4 + 0][row] = v.x; as[h4 * 4 + 1][row] = v.y;
      as[h4 * 4 + 2][row] = v.z; as[h4 * 4 + 3][row] = v.w;
      float4 w = *(const float4*)&Wm[(n0 + row) * H + kc + h4 * 4];
      bs[h4 * 4 + 0][row] = w.x; bs[h4 * 4 + 1][row] = w.y;
      bs[h4 * 4 + 2][row] = w.z; bs[h4 * 4 + 3][row] = w.w;
    }
    __syncthreads();
#pragma unroll
    for (int k = 0; k < 32; ++k) {
      float4 a4 = *(const float4*)&as[k][mm];
      float4 b4 = *(const float4*)&bs[k][nn];
      float av[4] = {a4.x, a4.y, a4.z, a4.w};
      float bv[4] = {b4.x, b4.y, b4.z, b4.w};
#pragma unroll
      for (int i = 0; i < 4; ++i)
#pragma unroll
        for (int j = 0; j < 4; ++j) acc[i][j] = fmaf(av[i], bv[j], acc[i][j]);
    }
    __syncthreads();
  }
  const int ncol0 = nblk * 64;
#pragma unroll
  for (int i = 0; i < 4; ++i) {
    float4 o;
    o.x = acc[i][0] + bias[n0 + nn + 0];
    o.y = acc[i][1] + bias[n0 + nn + 1];
    o.z = acc[i][2] + bias[n0 + nn + 2];
    o.w = acc[i][3] + bias[n0 + nn + 3];
    *(float4*)&hij[(m0 + mm + i) * 1536 + ncol0 + nn] = o;
  }
}

// ---------------------------------------------------------------------------
// Stage 2: logits[b,a,c] = sum_h va[h] * tanh(hi[b,c,h] + hj[b,a,h])
// 32x32 (a,c) tile, 256 threads, 2x2 micro-tile. Per-element math is a single
// ascending-h fma chain with ops IDENTICAL to the round-1 kernel -> logits
// bit-identical -> top-k indices unchanged.
__global__ __launch_bounds__(256) void biaffine2(
    const float* __restrict__ hij, const float* __restrict__ va,
    float* __restrict__ logits) {
  __shared__ __align__(16) float his[16][34];  // [h][c]
  __shared__ __align__(16) float hjs[16][34];  // [h][a]
  __shared__ float vas[16];
  const int b = blockIdx.z;
  const int a0 = blockIdx.y * 32;
  const int c0 = blockIdx.x * 32;
  const int t = threadIdx.x;
  const int lh = t & 15;       // h for loads
  const int lr = t >> 4;       // 0..15 row for loads
  const int ca = (t & 15) * 2; // 2 c-cols per thread
  const int aa = (t >> 4) * 2; // 2 a-rows per thread
  float acc00 = 0.f, acc01 = 0.f, acc10 = 0.f, acc11 = 0.f;

  for (int hc = 0; hc < H; hc += 16) {
    his[lh][lr]      = hij[(b * S + c0 + lr) * 1536 + hc + lh];
    his[lh][lr + 16] = hij[(b * S + c0 + lr + 16) * 1536 + hc + lh];
    hjs[lh][lr]      = hij[(b * S + a0 + lr) * 1536 + 768 + hc + lh];
    hjs[lh][lr + 16] = hij[(b * S + a0 + lr + 16) * 1536 + 768 + hc + lh];
    if (t < 16) vas[t] = va[hc + t];
    __syncthreads();
#pragma unroll
    for (int h = 0; h < 16; ++h) {
      float v = vas[h];
      float2 xi = *(const float2*)&his[h][ca];
      float2 xj = *(const float2*)&hjs[h][aa];
      acc00 = fmaf(v, fast_tanh(xi.x + xj.x), acc00);
      acc01 = fmaf(v, fast_tanh(xi.y + xj.x), acc01);
      acc10 = fmaf(v, fast_tanh(xi.x + xj.y), acc10);
      acc11 = fmaf(v, fast_tanh(xi.y + xj.y), acc11);
    }
    __syncthreads();
  }
  float2 r0 = {acc00, acc01};
  float2 r1 = {acc10, acc11};
  *(float2*)&logits[(b * S + a0 + aa) * S + c0 + ca]     = r0;
  *(float2*)&logits[(b * S + a0 + aa + 1) * S + c0 + ca] = r1;
}

// ---------------------------------------------------------------------------
// Stage 3: top-4 over c for each (b,a) row; tie-break = smaller index.
__global__ __launch_bounds__(64) void topk_kernel(
    const float* __restrict__ logits, int* __restrict__ idx) {
  const int row = blockIdx.x;  // b*S + a
  const int lane = threadIdx.x;
  float v[4];
#pragma unroll
  for (int j = 0; j < 4; ++j) v[j] = logits[row * S + j * 64 + lane];
#pragma unroll
  for (int k = 0; k < TOPK; ++k) {
    float bestv = v[0];
    int besti = lane;
#pragma unroll
    for (int j = 1; j < 4; ++j) {
      int c = j * 64 + lane;
      if (v[j] > bestv) { bestv = v[j]; besti = c; }
    }
#pragma unroll
    for (int off = 32; off > 0; off >>= 1) {
      float ov = __shfl_xor(bestv, off);
      int oi = __shfl_xor(besti, off);
      if (ov > bestv || (ov == bestv && oi < besti)) { bestv = ov; besti = oi; }
    }
    int mj = besti >> 6, ml = besti & 63;
#pragma unroll
    for (int j = 0; j < 4; ++j)
      if (lane == ml && j == mj) v[j] = -3.402823466e38f;
    if (lane == 0) idx[row * TOPK + k] = besti;
  }
}

// ---------------------------------------------------------------------------
// Stage 4 (bf16 MFMA): hidden[r,o] = tanh( cat[r,:] . dense_w[o,:] + dense_b[o] )
// 64x64 tile, BK=32, 4 waves of 2x2 16x16x32 MFMA subtiles.
// A/B frag: row = lane&15, k = (lane>>4)*8 + j.  D: col=lane&15, row=(lane>>4)*4+reg.
__global__ __launch_bounds__(256) void dense_mfma(
    const __bf16* __restrict__ pooledb, const int* __restrict__ idx,
    const __bf16* __restrict__ wb, const float* __restrict__ dense_b,
    float* __restrict__ hidden) {
  __shared__ __align__(16) __bf16 As[64][40];  // [m][k], stride 40 bf16 = 80B (2-way banking, free)
  __shared__ __align__(16) __bf16 Bs[64][40];  // [n][k]
  const int m0 = blockIdx.x * 64;
  const int n0 = blockIdx.y * 64;
  const int t = threadIdx.x;
  const int srow = t >> 2;       // 0..63 staging row
  const int kq = (t & 3) * 8;    // staging k-offset (8 bf16 = 16B)
  // A row r = (b,s,k): dep half = pooled[b,s], head half = pooled[b, idx[b,s,k]]
  const int r = m0 + srow;
  const int kk = r & 3, s = (r >> 2) & 255, b = r >> 10;
  const __bf16* dep  = pooledb + (b * S + s) * H;
  const __bf16* head = pooledb + (b * S + idx[(b * S + s) * TOPK + kk]) * H;
  const __bf16* brow = wb + (size_t)(n0 + srow) * (2 * H);
  const int lane = t & 63;
  const int wave = t >> 6;
  const int wm = (wave & 1) * 32;
  const int wn = (wave >> 1) * 32;
  const int fm = lane & 15;
  const int quad = lane >> 4;
  floatx4 acc[2][2] = {};

  for (int kc = 0; kc < 2 * H; kc += 32) {
    const __bf16* ap = (kc < H) ? (dep + kc) : (head + (kc - H));
    *(bf16x8*)&As[srow][kq] = *(const bf16x8*)&ap[kq];
    *(bf16x8*)&Bs[srow][kq] = *(const bf16x8*)&brow[kc + kq];
    __syncthreads();
    bf16x8 af[2], bfr[2];
#pragma unroll
    for (int i = 0; i < 2; ++i) {
      af[i]  = *(const bf16x8*)&As[wm + i * 16 + fm][quad * 8];
      bfr[i] = *(const bf16x8*)&Bs[wn + i * 16 + fm][quad * 8];
    }
#pragma unroll
    for (int i = 0; i < 2; ++i)
#pragma unroll
      for (int j = 0; j < 2; ++j)
        acc[i][j] = __builtin_amdgcn_mfma_f32_16x16x32_bf16(af[i], bfr[j], acc[i][j], 0, 0, 0);
    __syncthreads();
  }
#pragma unroll
  for (int i = 0; i < 2; ++i)
#pragma unroll
    for (int j = 0; j < 2; ++j) {
      const int col = n0 + wn + j * 16 + fm;
      const float bias = dense_b[col];
#pragma unroll
      for (int rg = 0; rg < 4; ++rg) {
        const int row = m0 + wm + i * 16 + quad * 4 + rg;
        hidden[(size_t)row * H + col] = fast_tanh(acc[i][j][rg] + bias);
      }
    }
}

// ---------------------------------------------------------------------------
// Stage 5: type_logits[r,l] = hidden[r,:] . fc_w[l,:] + fc_b[l]
__global__ __launch_bounds__(64) void fc_kernel(
    const float* __restrict__ hidden, const float* __restrict__ fc_w,
    const float* __restrict__ fc_b, float* __restrict__ out_type) {
  const int r = blockIdx.x;
  const int lane = threadIdx.x;
  float acc[L] = {};
#pragma unroll
  for (int j = 0; j < H / 64; ++j) {
    int h = j * 64 + lane;
    float x = hidden[r * H + h];
#pragma unroll
    for (int l = 0; l < L; ++l) acc[l] = fmaf(x, fc_w[l * H + h], acc[l]);
  }
#pragma unroll
  for (int l = 0; l < L; ++l)
#pragma unroll
    for (int off = 32; off > 0; off >>= 1) acc[l] += __shfl_xor(acc[l], off);
  if (lane == 0) {
#pragma unroll
    for (int l = 0; l < L; ++l) out_type[r * L + l] = acc[l] + fc_b[l];
  }
}

// ---------------------------------------------------------------------------
extern "C" void kernel_launch(void* const* d_in, const int* in_sizes, int n_in,
                              void* d_out, int out_size, void* d_ws, size_t ws_size,
                              hipStream_t stream) {
  const float* pooled  = (const float*)d_in[0];
  const float* Wa_w    = (const float*)d_in[1];
  const float* Wa_b    = (const float*)d_in[2];
  const float* Ua_w    = (const float*)d_in[3];
  const float* Ua_b    = (const float*)d_in[4];
  const float* va_w    = (const float*)d_in[5];
  const float* dense_w = (const float*)d_in[6];
  const float* dense_b = (const float*)d_in[7];
  const float* fc_w    = (const float*)d_in[8];
  const float* fc_b    = (const float*)d_in[9];

  float* logits   = (float*)d_out;            // (4,256,256) = 262144
  float* out_type = logits + NB * S * S;      // (4,256,4,4) = 16384

  // ws layout (all 16B-aligned):
  float*  hij     = (float*)d_ws;                      // 1024x1536 f32 = 6 MB
  int*    idxbuf  = (int*)(hij + 1024 * 1536);         // 4096 ints
  float*  hidden  = (float*)(idxbuf + NB * S * TOPK);  // 4096x768 f32 = 12 MB
  __bf16* pooledb = (__bf16*)(hidden + 4096 * 768);    // 786432 bf16 = 1.5 MB
  __bf16* wbuf    = pooledb + NB * S * H;              // 1179648 bf16 = 2.25 MB

  cvt_kernel<<<dim3(1920), 256, 0, stream>>>(pooled, dense_w, pooledb, wbuf);
  proj_kernel<<<dim3(16, 24), 256, 0, stream>>>(pooled, Wa_w, Wa_b, Ua_w, Ua_b, hij);
  biaffine2<<<dim3(8, 8, 4), 256, 0, stream>>>(hij, va_w, logits);
  topk_kernel<<<dim3(1024), 64, 0, stream>>>(logits, idxbuf);
  dense_mfma<<<dim3(64, 12), 256, 0, stream>>>(pooledb, idxbuf, wbuf, dense_b, hidden);
  fc_kernel<<<dim3(4096), 64, 0, stream>>>(hidden, fc_w, fc_b, out_type);
}

// Round 3
// 250.440 us; speedup vs baseline: 1.5689x; 1.2062x over previous
//
#include <hip/hip_runtime.h>
#include <math.h>

#define H 768
#define S 256
#define NB 4      // batch
#define TOPK 4
#define L 4
#define NH 4      // biaffine h-split chunks (192 h each)

// 2/ln2: tanh(x) = 1 - 2/(2^(C*x)+1)
#define CSCALE 2.8853900817779268f

typedef __bf16 bf16x8 __attribute__((ext_vector_type(8)));
typedef float floatx4 __attribute__((ext_vector_type(4)));

// tanh via exp for the dense epilogue (unchanged from round 2, passing)
__device__ __forceinline__ float fast_tanh(float x) {
  float cx = fminf(15.f, fmaxf(-15.f, x));
  float e = __expf(cx + cx);
  return __fdividef(e - 1.f, e + 1.f);
}

// ---------------------------------------------------------------------------
// Stage 0a: split pooled and concat(Wa,Ua) into bf16 hi/lo pairs.
__global__ __launch_bounds__(256) void cvt1_kernel(
    const float* __restrict__ pooled, const float* __restrict__ Wa_w,
    const float* __restrict__ Ua_w, __bf16* __restrict__ Ah,
    __bf16* __restrict__ Al, __bf16* __restrict__ Wh, __bf16* __restrict__ Wl) {
  const int NA4 = (NB * S * H) / 4;       // 196608
  const int NW4 = (2 * H * H) / 4;        // 294912 (Wa then Ua)
  const int NWa4 = (H * H) / 4;           // 147456
  int i = blockIdx.x * 256 + threadIdx.x;
  if (i >= NA4 + NW4) return;
  float4 v;
  __bf16 *hi, *lo;
  if (i < NA4) {
    v = ((const float4*)pooled)[i];
    hi = Ah + i * 4; lo = Al + i * 4;
  } else {
    int w = i - NA4;
    v = (w < NWa4) ? ((const float4*)Wa_w)[w] : ((const float4*)Ua_w)[w - NWa4];
    hi = Wh + (size_t)w * 4; lo = Wl + (size_t)w * 4;
  }
  union { __bf16 h[4]; ushort4 u; } a, b;
  float f[4] = {v.x, v.y, v.z, v.w};
#pragma unroll
  for (int k = 0; k < 4; ++k) {
    __bf16 h = (__bf16)f[k];
    a.h[k] = h;
    b.h[k] = (__bf16)(f[k] - (float)h);
  }
  *(ushort4*)hi = a.u;
  *(ushort4*)lo = b.u;
}

// Stage 0b: dense_w -> bf16 (hi only). Runs AFTER proj (reuses Wh buffer).
__global__ __launch_bounds__(256) void cvt2_kernel(
    const float* __restrict__ w, __bf16* __restrict__ wb) {
  const int NW4 = (H * 2 * H) / 4;  // 294912
  int i = blockIdx.x * 256 + threadIdx.x;
  if (i >= NW4) return;
  float4 v = ((const float4*)w)[i];
  union { __bf16 h[4]; ushort4 u; } tmp;
  tmp.h[0] = (__bf16)v.x; tmp.h[1] = (__bf16)v.y;
  tmp.h[2] = (__bf16)v.z; tmp.h[3] = (__bf16)v.w;
  *(ushort4*)(wb + (size_t)i * 4) = tmp.u;
}

// ---------------------------------------------------------------------------
// Stage 1 (split-bf16 MFMA, fp32-class accuracy):
// hij[m][n] = CSCALE * (pooled[m,:] . W[n,:] + bias[n]),  W = concat(Wa, Ua) rows.
// x = xh + xl (two bf16); product via 4 MFMAs: hh + hl + lh + ll.
// 64x64 tile, BK=32, 4 waves of 2x2 16x16x32 subtiles (layout validated in dense_mfma).
__global__ __launch_bounds__(256) void proj_mfma(
    const __bf16* __restrict__ Ah, const __bf16* __restrict__ Al,
    const __bf16* __restrict__ Wh, const __bf16* __restrict__ Wl,
    const float* __restrict__ Wa_b, const float* __restrict__ Ua_b,
    float* __restrict__ hij) {
  __shared__ __align__(16) __bf16 Ahs[64][40];
  __shared__ __align__(16) __bf16 Als[64][40];
  __shared__ __align__(16) __bf16 Bhs[64][40];
  __shared__ __align__(16) __bf16 Bls[64][40];
  const int m0 = blockIdx.x * 64;
  const int n0 = blockIdx.y * 64;
  const int t = threadIdx.x;
  const int srow = t >> 2;
  const int kq = (t & 3) * 8;
  const __bf16* arh = Ah + (size_t)(m0 + srow) * H;
  const __bf16* arl = Al + (size_t)(m0 + srow) * H;
  const __bf16* brh = Wh + (size_t)(n0 + srow) * H;
  const __bf16* brl = Wl + (size_t)(n0 + srow) * H;
  const int lane = t & 63;
  const int wave = t >> 6;
  const int wm = (wave & 1) * 32;
  const int wn = (wave >> 1) * 32;
  const int fm = lane & 15;
  const int quad = lane >> 4;
  floatx4 acc[2][2] = {};

  for (int kc = 0; kc < H; kc += 32) {
    *(bf16x8*)&Ahs[srow][kq] = *(const bf16x8*)&arh[kc + kq];
    *(bf16x8*)&Als[srow][kq] = *(const bf16x8*)&arl[kc + kq];
    *(bf16x8*)&Bhs[srow][kq] = *(const bf16x8*)&brh[kc + kq];
    *(bf16x8*)&Bls[srow][kq] = *(const bf16x8*)&brl[kc + kq];
    __syncthreads();
    bf16x8 afh[2], afl[2], bfh[2], bfl[2];
#pragma unroll
    for (int i = 0; i < 2; ++i) {
      afh[i] = *(const bf16x8*)&Ahs[wm + i * 16 + fm][quad * 8];
      afl[i] = *(const bf16x8*)&Als[wm + i * 16 + fm][quad * 8];
      bfh[i] = *(const bf16x8*)&Bhs[wn + i * 16 + fm][quad * 8];
      bfl[i] = *(const bf16x8*)&Bls[wn + i * 16 + fm][quad * 8];
    }
#pragma unroll
    for (int i = 0; i < 2; ++i)
#pragma unroll
      for (int j = 0; j < 2; ++j) {
        acc[i][j] = __builtin_amdgcn_mfma_f32_16x16x32_bf16(afh[i], bfh[j], acc[i][j], 0, 0, 0);
        acc[i][j] = __builtin_amdgcn_mfma_f32_16x16x32_bf16(afh[i], bfl[j], acc[i][j], 0, 0, 0);
        acc[i][j] = __builtin_amdgcn_mfma_f32_16x16x32_bf16(afl[i], bfh[j], acc[i][j], 0, 0, 0);
        acc[i][j] = __builtin_amdgcn_mfma_f32_16x16x32_bf16(afl[i], bfl[j], acc[i][j], 0, 0, 0);
      }
    __syncthreads();
  }
#pragma unroll
  for (int i = 0; i < 2; ++i)
#pragma unroll
    for (int j = 0; j < 2; ++j) {
      const int col = n0 + wn + j * 16 + fm;
      const float bias = (col < H) ? Wa_b[col] : Ua_b[col - H];
#pragma unroll
      for (int rg = 0; rg < 4; ++rg) {
        const int row = m0 + wm + i * 16 + quad * 4 + rg;
        hij[(size_t)row * 1536 + col] = CSCALE * (acc[i][j][rg] + bias);
      }
    }
}

// ---------------------------------------------------------------------------
// Stage 2: partial[ch][b,a,c] = Sva_ch + sum_{h in ch} (-2 va[h]) / (2^(xi+xj)+1)
// where xi,xj are CSCALE-prescaled (done in proj epilogue).
// 32x32 (a,c) tile, 2x2/thread, h split into NH=4 chunks -> 1024 blocks.
__global__ __launch_bounds__(256) void biaffine3(
    const float* __restrict__ hij, const float* __restrict__ va,
    float* __restrict__ partials) {
  __shared__ __align__(16) float his[16][34];  // [h][c]
  __shared__ __align__(16) float hjs[16][34];  // [h][a]
  __shared__ float vas2[192];                  // -2*va over this chunk
  __shared__ float svas;                       // Sva_chunk
  const int z = blockIdx.z;
  const int b = z >> 2;
  const int ch = z & 3;
  const int hc0 = ch * 192;
  const int a0 = blockIdx.y * 32;
  const int c0 = blockIdx.x * 32;
  const int t = threadIdx.x;
  if (t < 192) vas2[t] = -2.f * va[hc0 + t];
  __syncthreads();
  if (t < 64) {
    float s = vas2[t] + vas2[t + 64] + vas2[t + 128];
#pragma unroll
    for (int off = 32; off > 0; off >>= 1) s += __shfl_xor(s, off);
    if (t == 0) svas = -0.5f * s;
  }
  const int lh = t & 15;
  const int lr = t >> 4;
  const int ca = (t & 15) * 2;
  const int aa = (t >> 4) * 2;
  float acc00 = 0.f, acc01 = 0.f, acc10 = 0.f, acc11 = 0.f;

  for (int hr = 0; hr < 192; hr += 16) {
    __syncthreads();
    his[lh][lr]      = hij[(size_t)(b * S + c0 + lr) * 1536 + hc0 + hr + lh];
    his[lh][lr + 16] = hij[(size_t)(b * S + c0 + lr + 16) * 1536 + hc0 + hr + lh];
    hjs[lh][lr]      = hij[(size_t)(b * S + a0 + lr) * 1536 + 768 + hc0 + hr + lh];
    hjs[lh][lr + 16] = hij[(size_t)(b * S + a0 + lr + 16) * 1536 + 768 + hc0 + hr + lh];
    __syncthreads();
#pragma unroll
    for (int h = 0; h < 16; ++h) {
      float v = vas2[hr + h];
      float2 xi = *(const float2*)&his[h][ca];
      float2 xj = *(const float2*)&hjs[h][aa];
      float d00 = exp2f(xi.x + xj.x) + 1.f;
      float d01 = exp2f(xi.y + xj.x) + 1.f;
      float d10 = exp2f(xi.x + xj.y) + 1.f;
      float d11 = exp2f(xi.y + xj.y) + 1.f;
      acc00 = fmaf(v, __fdividef(1.f, d00), acc00);
      acc01 = fmaf(v, __fdividef(1.f, d01), acc01);
      acc10 = fmaf(v, __fdividef(1.f, d10), acc10);
      acc11 = fmaf(v, __fdividef(1.f, d11), acc11);
    }
  }
  __syncthreads();
  const float sv = svas;
  float* pout = partials + (size_t)ch * (NB * S * S);
  float2 r0 = {acc00 + sv, acc01 + sv};
  float2 r1 = {acc10 + sv, acc11 + sv};
  *(float2*)&pout[(b * S + a0 + aa) * S + c0 + ca]     = r0;
  *(float2*)&pout[(b * S + a0 + aa + 1) * S + c0 + ca] = r1;
}

// ---------------------------------------------------------------------------
// Stage 3: combine 4 partials -> logits (d_out) + top-4 per row.
__global__ __launch_bounds__(64) void topk_kernel(
    const float* __restrict__ partials, float* __restrict__ logits,
    int* __restrict__ idx) {
  const int row = blockIdx.x;  // b*S + a
  const int lane = threadIdx.x;
  const int P = NB * S * S;
  float v[4];
#pragma unroll
  for (int j = 0; j < 4; ++j) {
    int c = row * S + j * 64 + lane;
    v[j] = ((partials[c] + partials[c + P]) + partials[c + 2 * P]) + partials[c + 3 * P];
    logits[c] = v[j];
  }
#pragma unroll
  for (int k = 0; k < TOPK; ++k) {
    float bestv = v[0];
    int besti = lane;
#pragma unroll
    for (int j = 1; j < 4; ++j) {
      int c = j * 64 + lane;
      if (v[j] > bestv) { bestv = v[j]; besti = c; }
    }
#pragma unroll
    for (int off = 32; off > 0; off >>= 1) {
      float ov = __shfl_xor(bestv, off);
      int oi = __shfl_xor(besti, off);
      if (ov > bestv || (ov == bestv && oi < besti)) { bestv = ov; besti = oi; }
    }
    int mj = besti >> 6, ml = besti & 63;
#pragma unroll
    for (int j = 0; j < 4; ++j)
      if (lane == ml && j == mj) v[j] = -3.402823466e38f;
    if (lane == 0) idx[row * TOPK + k] = besti;
  }
}

// ---------------------------------------------------------------------------
// Stage 4 (bf16 MFMA, unchanged structure from round 2 — passing):
__global__ __launch_bounds__(256) void dense_mfma(
    const __bf16* __restrict__ pooledb, const int* __restrict__ idx,
    const __bf16* __restrict__ wb, const float* __restrict__ dense_b,
    float* __restrict__ hidden) {
  __shared__ __align__(16) __bf16 As[64][40];
  __shared__ __align__(16) __bf16 Bs[64][40];
  const int m0 = blockIdx.x * 64;
  const int n0 = blockIdx.y * 64;
  const int t = threadIdx.x;
  const int srow = t >> 2;
  const int kq = (t & 3) * 8;
  const int r = m0 + srow;
  const int kk = r & 3, s = (r >> 2) & 255, b = r >> 10;
  const __bf16* dep  = pooledb + (b * S + s) * H;
  const __bf16* head = pooledb + (b * S + idx[(b * S + s) * TOPK + kk]) * H;
  const __bf16* brow = wb + (size_t)(n0 + srow) * (2 * H);
  const int lane = t & 63;
  const int wave = t >> 6;
  const int wm = (wave & 1) * 32;
  const int wn = (wave >> 1) * 32;
  const int fm = lane & 15;
  const int quad = lane >> 4;
  floatx4 acc[2][2] = {};

  for (int kc = 0; kc < 2 * H; kc += 32) {
    const __bf16* ap = (kc < H) ? (dep + kc) : (head + (kc - H));
    *(bf16x8*)&As[srow][kq] = *(const bf16x8*)&ap[kq];
    *(bf16x8*)&Bs[srow][kq] = *(const bf16x8*)&brow[kc + kq];
    __syncthreads();
    bf16x8 af[2], bfr[2];
#pragma unroll
    for (int i = 0; i < 2; ++i) {
      af[i]  = *(const bf16x8*)&As[wm + i * 16 + fm][quad * 8];
      bfr[i] = *(const bf16x8*)&Bs[wn + i * 16 + fm][quad * 8];
    }
#pragma unroll
    for (int i = 0; i < 2; ++i)
#pragma unroll
      for (int j = 0; j < 2; ++j)
        acc[i][j] = __builtin_amdgcn_mfma_f32_16x16x32_bf16(af[i], bfr[j], acc[i][j], 0, 0, 0);
    __syncthreads();
  }
#pragma unroll
  for (int i = 0; i < 2; ++i)
#pragma unroll
    for (int j = 0; j < 2; ++j) {
      const int col = n0 + wn + j * 16 + fm;
      const float bias = dense_b[col];
#pragma unroll
      for (int rg = 0; rg < 4; ++rg) {
        const int row = m0 + wm + i * 16 + quad * 4 + rg;
        hidden[(size_t)row * H + col] = fast_tanh(acc[i][j][rg] + bias);
      }
    }
}

// ---------------------------------------------------------------------------
// Stage 5: type_logits[r,l] = hidden[r,:] . fc_w[l,:] + fc_b[l]
__global__ __launch_bounds__(64) void fc_kernel(
    const float* __restrict__ hidden, const float* __restrict__ fc_w,
    const float* __restrict__ fc_b, float* __restrict__ out_type) {
  const int r = blockIdx.x;
  const int lane = threadIdx.x;
  float acc[L] = {};
#pragma unroll
  for (int j = 0; j < H / 64; ++j) {
    int h = j * 64 + lane;
    float x = hidden[r * H + h];
#pragma unroll
    for (int l = 0; l < L; ++l) acc[l] = fmaf(x, fc_w[l * H + h], acc[l]);
  }
#pragma unroll
  for (int l = 0; l < L; ++l)
#pragma unroll
    for (int off = 32; off > 0; off >>= 1) acc[l] += __shfl_xor(acc[l], off);
  if (lane == 0) {
#pragma unroll
    for (int l = 0; l < L; ++l) out_type[r * L + l] = acc[l] + fc_b[l];
  }
}

// ---------------------------------------------------------------------------
extern "C" void kernel_launch(void* const* d_in, const int* in_sizes, int n_in,
                              void* d_out, int out_size, void* d_ws, size_t ws_size,
                              hipStream_t stream) {
  const float* pooled  = (const float*)d_in[0];
  const float* Wa_w    = (const float*)d_in[1];
  const float* Wa_b    = (const float*)d_in[2];
  const float* Ua_w    = (const float*)d_in[3];
  const float* Ua_b    = (const float*)d_in[4];
  const float* va_w    = (const float*)d_in[5];
  const float* dense_w = (const float*)d_in[6];
  const float* dense_b = (const float*)d_in[7];
  const float* fc_w    = (const float*)d_in[8];
  const float* fc_b    = (const float*)d_in[9];

  float* logits   = (float*)d_out;            // (4,256,256)
  float* out_type = logits + NB * S * S;      // (4,256,4,4)

  // ws layout:
  float*  hij    = (float*)d_ws;                       // 1,572,864 f (6 MB)
  float*  hidden = hij + 1572864;                      // 3,145,728 f (12 MB)
  // partials alias hidden[0 .. 1,048,576) — consumed by topk BEFORE dense writes hidden.
  float*  partials = hidden;
  // Wl aliases hidden[1,048,576 .. +589,824) — consumed by proj BEFORE biaffine/dense write.
  __bf16* Wl = (__bf16*)(hidden + 1048576);
  int*    idxbuf = (int*)(hidden + 3145728);           // 4096 ints
  __bf16* Ah = (__bf16*)(idxbuf + NB * S * TOPK);      // 786,432 bf16
  __bf16* Al = Ah + 786432;                            // 786,432 bf16
  __bf16* Wh = Al + 786432;                            // 1,179,648 bf16 (reused as wb by cvt2)

  cvt1_kernel<<<dim3(1920), 256, 0, stream>>>(pooled, Wa_w, Ua_w, Ah, Al, Wh, Wl);
  proj_mfma<<<dim3(16, 24), 256, 0, stream>>>(Ah, Al, Wh, Wl, Wa_b, Ua_b, hij);
  cvt2_kernel<<<dim3(1152), 256, 0, stream>>>(dense_w, Wh);  // Wh now holds bf16 dense_w
  biaffine3<<<dim3(8, 8, NB * NH), 256, 0, stream>>>(hij, va_w, partials);
  topk_kernel<<<dim3(1024), 64, 0, stream>>>(partials, logits, idxbuf);
  dense_mfma<<<dim3(64, 12), 256, 0, stream>>>(Ah, idxbuf, Wh, dense_b, hidden);
  fc_kernel<<<dim3(4096), 64, 0, stream>>>(hidden, fc_w, fc_b, out_type);
}

// Round 4
// 182.009 us; speedup vs baseline: 2.1587x; 1.3760x over previous
//
#include <hip/hip_runtime.h>
#include <math.h>

#define H 768
#define S 256
#define NB 4      // batch
#define TOPK 4
#define L 4
#define NH 4      // biaffine h-split chunks (192 h each)

// 2/ln2: tanh(x) = 1 - 2/(2^(C*x)+1)
#define CSCALE 2.8853900817779268f

typedef __bf16 bf16x8 __attribute__((ext_vector_type(8)));
typedef float floatx4 __attribute__((ext_vector_type(4)));

// Native-rate transcendentals (v_exp_f32 / v_rcp_f32, ~1 ULP). Without
// -ffast-math, exp2f() is an OCML precise libcall (~20 VALU ops) -- that was
// round 3's biaffine bottleneck (VALUBusy 90% at 6x the expected issue count).
__device__ __forceinline__ float exp2_native(float x) {
#if __has_builtin(__builtin_amdgcn_exp2f)
  return __builtin_amdgcn_exp2f(x);
#else
  float r; asm("v_exp_f32 %0, %1" : "=v"(r) : "v"(x)); return r;
#endif
}
__device__ __forceinline__ float rcp_native(float x) {
#if __has_builtin(__builtin_amdgcn_rcpf)
  return __builtin_amdgcn_rcpf(x);
#else
  float r; asm("v_rcp_f32 %0, %1" : "=v"(r) : "v"(x)); return r;
#endif
}

// tanh for the dense epilogue (unchanged from round 2/3 -- passing)
__device__ __forceinline__ float fast_tanh(float x) {
  float cx = fminf(15.f, fmaxf(-15.f, x));
  float e = __expf(cx + cx);
  return __fdividef(e - 1.f, e + 1.f);
}

// ---------------------------------------------------------------------------
// Stage 0: split pooled + concat(Wa,Ua) into bf16 hi/lo; dense_w -> bf16 hi.
__global__ __launch_bounds__(256) void cvt_kernel(
    const float* __restrict__ pooled, const float* __restrict__ Wa_w,
    const float* __restrict__ Ua_w, const float* __restrict__ dense_w,
    __bf16* __restrict__ Ah, __bf16* __restrict__ Al,
    __bf16* __restrict__ Wh, __bf16* __restrict__ Wl,
    __bf16* __restrict__ wdense) {
  const int NA4 = (NB * S * H) / 4;       // 196608
  const int NW4 = (2 * H * H) / 4;        // 294912 (Wa then Ua)
  const int NWa4 = (H * H) / 4;           // 147456
  const int ND4 = (H * 2 * H) / 4;        // 294912
  int i = blockIdx.x * 256 + threadIdx.x;
  if (i >= NA4 + NW4 + ND4) return;
  if (i >= NA4 + NW4) {
    int w = i - NA4 - NW4;
    float4 v = ((const float4*)dense_w)[w];
    union { __bf16 h[4]; ushort4 u; } tmp;
    tmp.h[0] = (__bf16)v.x; tmp.h[1] = (__bf16)v.y;
    tmp.h[2] = (__bf16)v.z; tmp.h[3] = (__bf16)v.w;
    *(ushort4*)(wdense + (size_t)w * 4) = tmp.u;
    return;
  }
  float4 v;
  __bf16 *hi, *lo;
  if (i < NA4) {
    v = ((const float4*)pooled)[i];
    hi = Ah + i * 4; lo = Al + i * 4;
  } else {
    int w = i - NA4;
    v = (w < NWa4) ? ((const float4*)Wa_w)[w] : ((const float4*)Ua_w)[w - NWa4];
    hi = Wh + (size_t)w * 4; lo = Wl + (size_t)w * 4;
  }
  union { __bf16 h[4]; ushort4 u; } a, b;
  float f[4] = {v.x, v.y, v.z, v.w};
#pragma unroll
  for (int k = 0; k < 4; ++k) {
    __bf16 h = (__bf16)f[k];
    a.h[k] = h;
    b.h[k] = (__bf16)(f[k] - (float)h);
  }
  *(ushort4*)hi = a.u;
  *(ushort4*)lo = b.u;
}

// ---------------------------------------------------------------------------
// Stage 1 (split-bf16 MFMA): hij[m][n] = CSCALE*(pooled[m,:].W[n,:] + bias[n]).
// x = xh + xl; product via 3 MFMAs (hh + hl + lh; ll term is ~2^-18 rel -> dropped).
__global__ __launch_bounds__(256) void proj_mfma(
    const __bf16* __restrict__ Ah, const __bf16* __restrict__ Al,
    const __bf16* __restrict__ Wh, const __bf16* __restrict__ Wl,
    const float* __restrict__ Wa_b, const float* __restrict__ Ua_b,
    float* __restrict__ hij) {
  __shared__ __align__(16) __bf16 Ahs[64][40];
  __shared__ __align__(16) __bf16 Als[64][40];
  __shared__ __align__(16) __bf16 Bhs[64][40];
  __shared__ __align__(16) __bf16 Bls[64][40];
  const int m0 = blockIdx.x * 64;
  const int n0 = blockIdx.y * 64;
  const int t = threadIdx.x;
  const int srow = t >> 2;
  const int kq = (t & 3) * 8;
  const __bf16* arh = Ah + (size_t)(m0 + srow) * H;
  const __bf16* arl = Al + (size_t)(m0 + srow) * H;
  const __bf16* brh = Wh + (size_t)(n0 + srow) * H;
  const __bf16* brl = Wl + (size_t)(n0 + srow) * H;
  const int lane = t & 63;
  const int wave = t >> 6;
  const int wm = (wave & 1) * 32;
  const int wn = (wave >> 1) * 32;
  const int fm = lane & 15;
  const int quad = lane >> 4;
  floatx4 acc[2][2] = {};

  for (int kc = 0; kc < H; kc += 32) {
    *(bf16x8*)&Ahs[srow][kq] = *(const bf16x8*)&arh[kc + kq];
    *(bf16x8*)&Als[srow][kq] = *(const bf16x8*)&arl[kc + kq];
    *(bf16x8*)&Bhs[srow][kq] = *(const bf16x8*)&brh[kc + kq];
    *(bf16x8*)&Bls[srow][kq] = *(const bf16x8*)&brl[kc + kq];
    __syncthreads();
    bf16x8 afh[2], afl[2], bfh[2], bfl[2];
#pragma unroll
    for (int i = 0; i < 2; ++i) {
      afh[i] = *(const bf16x8*)&Ahs[wm + i * 16 + fm][quad * 8];
      afl[i] = *(const bf16x8*)&Als[wm + i * 16 + fm][quad * 8];
      bfh[i] = *(const bf16x8*)&Bhs[wn + i * 16 + fm][quad * 8];
      bfl[i] = *(const bf16x8*)&Bls[wn + i * 16 + fm][quad * 8];
    }
#pragma unroll
    for (int i = 0; i < 2; ++i)
#pragma unroll
      for (int j = 0; j < 2; ++j) {
        acc[i][j] = __builtin_amdgcn_mfma_f32_16x16x32_bf16(afh[i], bfh[j], acc[i][j], 0, 0, 0);
        acc[i][j] = __builtin_amdgcn_mfma_f32_16x16x32_bf16(afh[i], bfl[j], acc[i][j], 0, 0, 0);
        acc[i][j] = __builtin_amdgcn_mfma_f32_16x16x32_bf16(afl[i], bfh[j], acc[i][j], 0, 0, 0);
      }
    __syncthreads();
  }
#pragma unroll
  for (int i = 0; i < 2; ++i)
#pragma unroll
    for (int j = 0; j < 2; ++j) {
      const int col = n0 + wn + j * 16 + fm;
      const float bias = (col < H) ? Wa_b[col] : Ua_b[col - H];
#pragma unroll
      for (int rg = 0; rg < 4; ++rg) {
        const int row = m0 + wm + i * 16 + quad * 4 + rg;
        hij[(size_t)row * 1536 + col] = CSCALE * (acc[i][j][rg] + bias);
      }
    }
}

// ---------------------------------------------------------------------------
// Stage 2: partial[ch][b,a,c] = Sva_ch + sum_{h in ch} (-2 va[h]) * rcp(2^(xi+xj)+1)
// xi,xj CSCALE-prescaled in proj. 32x32 tile, 2x2/thread, NH=4 chunks.
__global__ __launch_bounds__(256) void biaffine3(
    const float* __restrict__ hij, const float* __restrict__ va,
    float* __restrict__ partials) {
  __shared__ __align__(16) float his[16][34];  // [h][c]
  __shared__ __align__(16) float hjs[16][34];  // [h][a]
  __shared__ __align__(16) float vas2[192];    // -2*va over this chunk
  __shared__ float svas;
  const int z = blockIdx.z;
  const int b = z >> 2;
  const int ch = z & 3;
  const int hc0 = ch * 192;
  const int a0 = blockIdx.y * 32;
  const int c0 = blockIdx.x * 32;
  const int t = threadIdx.x;
  if (t < 192) vas2[t] = -2.f * va[hc0 + t];
  __syncthreads();
  if (t < 64) {
    float s = vas2[t] + vas2[t + 64] + vas2[t + 128];
#pragma unroll
    for (int off = 32; off > 0; off >>= 1) s += __shfl_xor(s, off);
    if (t == 0) svas = -0.5f * s;
  }
  const int lh = t & 15;
  const int lr = t >> 4;
  const int ca = (t & 15) * 2;
  const int aa = (t >> 4) * 2;
  float acc00 = 0.f, acc01 = 0.f, acc10 = 0.f, acc11 = 0.f;

  for (int hr = 0; hr < 192; hr += 16) {
    __syncthreads();
    his[lh][lr]      = hij[(size_t)(b * S + c0 + lr) * 1536 + hc0 + hr + lh];
    his[lh][lr + 16] = hij[(size_t)(b * S + c0 + lr + 16) * 1536 + hc0 + hr + lh];
    hjs[lh][lr]      = hij[(size_t)(b * S + a0 + lr) * 1536 + 768 + hc0 + hr + lh];
    hjs[lh][lr + 16] = hij[(size_t)(b * S + a0 + lr + 16) * 1536 + 768 + hc0 + hr + lh];
    __syncthreads();
    float vreg[16];
    *(float4*)&vreg[0]  = *(const float4*)&vas2[hr + 0];
    *(float4*)&vreg[4]  = *(const float4*)&vas2[hr + 4];
    *(float4*)&vreg[8]  = *(const float4*)&vas2[hr + 8];
    *(float4*)&vreg[12] = *(const float4*)&vas2[hr + 12];
#pragma unroll
    for (int h = 0; h < 16; ++h) {
      float v = vreg[h];
      float2 xi = *(const float2*)&his[h][ca];
      float2 xj = *(const float2*)&hjs[h][aa];
      acc00 = fmaf(v, rcp_native(exp2_native(xi.x + xj.x) + 1.f), acc00);
      acc01 = fmaf(v, rcp_native(exp2_native(xi.y + xj.x) + 1.f), acc01);
      acc10 = fmaf(v, rcp_native(exp2_native(xi.x + xj.y) + 1.f), acc10);
      acc11 = fmaf(v, rcp_native(exp2_native(xi.y + xj.y) + 1.f), acc11);
    }
  }
  __syncthreads();
  const float sv = svas;
  float* pout = partials + (size_t)ch * (NB * S * S);
  float2 r0 = {acc00 + sv, acc01 + sv};
  float2 r1 = {acc10 + sv, acc11 + sv};
  *(float2*)&pout[(b * S + a0 + aa) * S + c0 + ca]     = r0;
  *(float2*)&pout[(b * S + a0 + aa + 1) * S + c0 + ca] = r1;
}

// ---------------------------------------------------------------------------
// Stage 3: combine 4 partials -> logits (d_out) + top-4 per row.
__global__ __launch_bounds__(64) void topk_kernel(
    const float* __restrict__ partials, float* __restrict__ logits,
    int* __restrict__ idx) {
  const int row = blockIdx.x;  // b*S + a
  const int lane = threadIdx.x;
  const int P = NB * S * S;
  float v[4];
#pragma unroll
  for (int j = 0; j < 4; ++j) {
    int c = row * S + j * 64 + lane;
    v[j] = ((partials[c] + partials[c + P]) + partials[c + 2 * P]) + partials[c + 3 * P];
    logits[c] = v[j];
  }
#pragma unroll
  for (int k = 0; k < TOPK; ++k) {
    float bestv = v[0];
    int besti = lane;
#pragma unroll
    for (int j = 1; j < 4; ++j) {
      int c = j * 64 + lane;
      if (v[j] > bestv) { bestv = v[j]; besti = c; }
    }
#pragma unroll
    for (int off = 32; off > 0; off >>= 1) {
      float ov = __shfl_xor(bestv, off);
      int oi = __shfl_xor(besti, off);
      if (ov > bestv || (ov == bestv && oi < besti)) { bestv = ov; besti = oi; }
    }
    int mj = besti >> 6, ml = besti & 63;
#pragma unroll
    for (int j = 0; j < 4; ++j)
      if (lane == ml && j == mj) v[j] = -3.402823466e38f;
    if (lane == 0) idx[row * TOPK + k] = besti;
  }
}

// ---------------------------------------------------------------------------
// Stage 4 (bf16 MFMA): hidden[r,o] = tanh(cat[r,:].dense_w[o,:] + dense_b[o]).
// Output stored as bf16 (halves fc traffic; +~1e-3 on type logits, 20x margin).
__global__ __launch_bounds__(256) void dense_mfma(
    const __bf16* __restrict__ pooledb, const int* __restrict__ idx,
    const __bf16* __restrict__ wb, const float* __restrict__ dense_b,
    __bf16* __restrict__ hiddenb) {
  __shared__ __align__(16) __bf16 As[64][40];
  __shared__ __align__(16) __bf16 Bs[64][40];
  const int m0 = blockIdx.x * 64;
  const int n0 = blockIdx.y * 64;
  const int t = threadIdx.x;
  const int srow = t >> 2;
  const int kq = (t & 3) * 8;
  const int r = m0 + srow;
  const int kk = r & 3, s = (r >> 2) & 255, b = r >> 10;
  const __bf16* dep  = pooledb + (b * S + s) * H;
  const __bf16* head = pooledb + (b * S + idx[(b * S + s) * TOPK + kk]) * H;
  const __bf16* brow = wb + (size_t)(n0 + srow) * (2 * H);
  const int lane = t & 63;
  const int wave = t >> 6;
  const int wm = (wave & 1) * 32;
  const int wn = (wave >> 1) * 32;
  const int fm = lane & 15;
  const int quad = lane >> 4;
  floatx4 acc[2][2] = {};

  for (int kc = 0; kc < 2 * H; kc += 32) {
    const __bf16* ap = (kc < H) ? (dep + kc) : (head + (kc - H));
    *(bf16x8*)&As[srow][kq] = *(const bf16x8*)&ap[kq];
    *(bf16x8*)&Bs[srow][kq] = *(const bf16x8*)&brow[kc + kq];
    __syncthreads();
    bf16x8 af[2], bfr[2];
#pragma unroll
    for (int i = 0; i < 2; ++i) {
      af[i]  = *(const bf16x8*)&As[wm + i * 16 + fm][quad * 8];
      bfr[i] = *(const bf16x8*)&Bs[wn + i * 16 + fm][quad * 8];
    }
#pragma unroll
    for (int i = 0; i < 2; ++i)
#pragma unroll
      for (int j = 0; j < 2; ++j)
        acc[i][j] = __builtin_amdgcn_mfma_f32_16x16x32_bf16(af[i], bfr[j], acc[i][j], 0, 0, 0);
    __syncthreads();
  }
#pragma unroll
  for (int i = 0; i < 2; ++i)
#pragma unroll
    for (int j = 0; j < 2; ++j) {
      const int col = n0 + wn + j * 16 + fm;
      const float bias = dense_b[col];
#pragma unroll
      for (int rg = 0; rg < 4; ++rg) {
        const int row = m0 + wm + i * 16 + quad * 4 + rg;
        hiddenb[(size_t)row * H + col] = (__bf16)fast_tanh(acc[i][j][rg] + bias);
      }
    }
}

// ---------------------------------------------------------------------------
// Stage 5: type_logits[r,l] = hidden[r,:] . fc_w[l,:] + fc_b[l]  (bf16 hidden)
__global__ __launch_bounds__(64) void fc_kernel(
    const __bf16* __restrict__ hiddenb, const float* __restrict__ fc_w,
    const float* __restrict__ fc_b, float* __restrict__ out_type) {
  const int r = blockIdx.x;
  const int lane = threadIdx.x;
  float acc[L] = {};
#pragma unroll
  for (int j = 0; j < H / 64; ++j) {
    int h = j * 64 + lane;
    float x = (float)hiddenb[r * H + h];
#pragma unroll
    for (int l = 0; l < L; ++l) acc[l] = fmaf(x, fc_w[l * H + h], acc[l]);
  }
#pragma unroll
  for (int l = 0; l < L; ++l)
#pragma unroll
    for (int off = 32; off > 0; off >>= 1) acc[l] += __shfl_xor(acc[l], off);
  if (lane == 0) {
#pragma unroll
    for (int l = 0; l < L; ++l) out_type[r * L + l] = acc[l] + fc_b[l];
  }
}

// ---------------------------------------------------------------------------
extern "C" void kernel_launch(void* const* d_in, const int* in_sizes, int n_in,
                              void* d_out, int out_size, void* d_ws, size_t ws_size,
                              hipStream_t stream) {
  const float* pooled  = (const float*)d_in[0];
  const float* Wa_w    = (const float*)d_in[1];
  const float* Wa_b    = (const float*)d_in[2];
  const float* Ua_w    = (const float*)d_in[3];
  const float* Ua_b    = (const float*)d_in[4];
  const float* va_w    = (const float*)d_in[5];
  const float* dense_w = (const float*)d_in[6];
  const float* dense_b = (const float*)d_in[7];
  const float* fc_w    = (const float*)d_in[8];
  const float* fc_b    = (const float*)d_in[9];

  float* logits   = (float*)d_out;            // (4,256,256)
  float* out_type = logits + NB * S * S;      // (4,256,4,4)

  // ws layout (aliasing audited against launch order):
  float*  hij = (float*)d_ws;                 // 1,572,864 f (6 MB)
  float*  big = hij + 1572864;                // 3,145,728 f (12 MB) region:
  float*  partials = big;                     //   [0 .. 1,048,576 f): biaffine -> topk
  __bf16* hiddenb  = (__bf16*)big;            //   [0 .. 786,432 f) as bf16: dense (post-topk) -> fc
  __bf16* Wl       = (__bf16*)(big + 1048576);//   [1,048,576 .. 1,638,400 f): cvt -> proj
  __bf16* wdense   = (__bf16*)(big + 1638400);//   [1,638,400 .. 2,228,224 f): cvt -> dense
  int*    idxbuf = (int*)(big + 3145728);     // 4096 ints
  __bf16* Ah = (__bf16*)(idxbuf + NB * S * TOPK);  // 786,432 bf16
  __bf16* Al = Ah + 786432;                        // 786,432 bf16
  __bf16* Wh = Al + 786432;                        // 1,179,648 bf16

  cvt_kernel<<<dim3(3072), 256, 0, stream>>>(pooled, Wa_w, Ua_w, dense_w,
                                             Ah, Al, Wh, Wl, wdense);
  proj_mfma<<<dim3(16, 24), 256, 0, stream>>>(Ah, Al, Wh, Wl, Wa_b, Ua_b, hij);
  biaffine3<<<dim3(8, 8, NB * NH), 256, 0, stream>>>(hij, va_w, partials);
  topk_kernel<<<dim3(1024), 64, 0, stream>>>(partials, logits, idxbuf);
  dense_mfma<<<dim3(64, 12), 256, 0, stream>>>(Ah, idxbuf, wdense, dense_b, hiddenb);
  fc_kernel<<<dim3(4096), 64, 0, stream>>>(hiddenb, fc_w, fc_b, out_type);
}

// Round 5
// 179.937 us; speedup vs baseline: 2.1836x; 1.0115x over previous
//
#include <hip/hip_runtime.h>
#include <math.h>

#define H 768
#define S 256
#define NB 4      // batch
#define TOPK 4
#define L 4
#define NH 4      // biaffine h-split chunks (192 h each)

// 2/ln2: tanh(x) = 1 - 2/(2^(C*x)+1)
#define CSCALE 2.8853900817779268f

typedef __bf16 bf16x8 __attribute__((ext_vector_type(8)));
typedef __bf16 bf16x4 __attribute__((ext_vector_type(4)));
typedef float floatx4 __attribute__((ext_vector_type(4)));

// Native-rate transcendentals (v_exp_f32 / v_rcp_f32). exp2f() without
// -ffast-math is an OCML precise libcall (~20 VALU ops) -- round 3's lesson.
__device__ __forceinline__ float exp2_native(float x) {
#if __has_builtin(__builtin_amdgcn_exp2f)
  return __builtin_amdgcn_exp2f(x);
#else
  float r; asm("v_exp_f32 %0, %1" : "=v"(r) : "v"(x)); return r;
#endif
}
__device__ __forceinline__ float rcp_native(float x) {
#if __has_builtin(__builtin_amdgcn_rcpf)
  return __builtin_amdgcn_rcpf(x);
#else
  float r; asm("v_rcp_f32 %0, %1" : "=v"(r) : "v"(x)); return r;
#endif
}

// tanh for the dense epilogue (passing since round 2; __expf is native-rate)
__device__ __forceinline__ float fast_tanh(float x) {
  float cx = fminf(15.f, fmaxf(-15.f, x));
  float e = __expf(cx + cx);
  return __fdividef(e - 1.f, e + 1.f);
}

// ---------------------------------------------------------------------------
// Stage 1 (split-bf16 MFMA, on-the-fly fp32->hi/lo conversion):
// hij[m][n] = CSCALE*(pooled[m,:].W[n,:] + bias[n]),  W = concat(Wa,Ua) rows.
// 32x64 tile -> grid 32x24 = 768 blocks = exactly 3 blocks/CU (balanced).
// 4 waves; wave w computes rows 0..31 x cols w*16..w*16+15 (2 subtiles over m).
__global__ __launch_bounds__(256) void proj_mfma(
    const float* __restrict__ pooled, const float* __restrict__ Wa_w,
    const float* __restrict__ Ua_w, const float* __restrict__ Wa_b,
    const float* __restrict__ Ua_b, float* __restrict__ hij) {
  __shared__ __align__(16) __bf16 Ahs[32][40];
  __shared__ __align__(16) __bf16 Als[32][40];
  __shared__ __align__(16) __bf16 Bhs[64][40];
  __shared__ __align__(16) __bf16 Bls[64][40];
  const int m0 = blockIdx.x * 32;
  const int n0 = blockIdx.y * 64;
  const int t = threadIdx.x;
  // A staging: 32 rows x 32 k; thread: row = t>>3, 4 k-floats at (t&7)*4
  const int arow = t >> 3;
  const int kq4 = (t & 7) * 4;
  const float* Arow = pooled + (size_t)(m0 + arow) * H;
  // B staging: 64 rows x 32 k; thread: row = t>>2, 8 k-floats at (t&3)*8
  const int brow = t >> 2;
  const int kq8 = (t & 3) * 8;
  const int ncol = n0 + brow;
  const float* Brow = (ncol < H) ? (Wa_w + (size_t)ncol * H)
                                 : (Ua_w + (size_t)(ncol - H) * H);
  const int lane = t & 63;
  const int wave = t >> 6;
  const int wn = wave * 16;
  const int fm = lane & 15;
  const int quad = lane >> 4;
  floatx4 acc[2] = {};

  for (int kc = 0; kc < H; kc += 32) {
    // A: 1 float4 -> 4 hi + 4 lo
    float4 av = *(const float4*)&Arow[kc + kq4];
    {
      float f[4] = {av.x, av.y, av.z, av.w};
      union { __bf16 h[4]; ushort4 u; } ah, al;
#pragma unroll
      for (int k = 0; k < 4; ++k) {
        __bf16 hv = (__bf16)f[k];
        ah.h[k] = hv;
        al.h[k] = (__bf16)(f[k] - (float)hv);
      }
      *(ushort4*)&Ahs[arow][kq4] = ah.u;
      *(ushort4*)&Als[arow][kq4] = al.u;
    }
    // B: 2 float4 -> 8 hi + 8 lo
    {
      float4 w0 = *(const float4*)&Brow[kc + kq8];
      float4 w1 = *(const float4*)&Brow[kc + kq8 + 4];
      float f[8] = {w0.x, w0.y, w0.z, w0.w, w1.x, w1.y, w1.z, w1.w};
      bf16x8 bh, bl;
#pragma unroll
      for (int k = 0; k < 8; ++k) {
        __bf16 hv = (__bf16)f[k];
        bh[k] = hv;
        bl[k] = (__bf16)(f[k] - (float)hv);
      }
      *(bf16x8*)&Bhs[brow][kq8] = bh;
      *(bf16x8*)&Bls[brow][kq8] = bl;
    }
    __syncthreads();
    bf16x8 afh[2], afl[2], bfh, bfl;
#pragma unroll
    for (int i = 0; i < 2; ++i) {
      afh[i] = *(const bf16x8*)&Ahs[i * 16 + fm][quad * 8];
      afl[i] = *(const bf16x8*)&Als[i * 16 + fm][quad * 8];
    }
    bfh = *(const bf16x8*)&Bhs[wn + fm][quad * 8];
    bfl = *(const bf16x8*)&Bls[wn + fm][quad * 8];
#pragma unroll
    for (int i = 0; i < 2; ++i) {
      acc[i] = __builtin_amdgcn_mfma_f32_16x16x32_bf16(afh[i], bfh, acc[i], 0, 0, 0);
      acc[i] = __builtin_amdgcn_mfma_f32_16x16x32_bf16(afh[i], bfl, acc[i], 0, 0, 0);
      acc[i] = __builtin_amdgcn_mfma_f32_16x16x32_bf16(afl[i], bfh, acc[i], 0, 0, 0);
    }
    __syncthreads();
  }
  const int col = n0 + wn + fm;
  const float bias = (col < H) ? Wa_b[col] : Ua_b[col - H];
#pragma unroll
  for (int i = 0; i < 2; ++i)
#pragma unroll
    for (int rg = 0; rg < 4; ++rg) {
      const int row = m0 + i * 16 + quad * 4 + rg;
      hij[(size_t)row * 1536 + col] = CSCALE * (acc[i][rg] + bias);
    }
}

// ---------------------------------------------------------------------------
// Stage 2 (software-pipelined): partial[ch][b,a,c] = Sva_ch +
//   sum_{h in ch} (-2 va[h]) * rcp(2^(xi+xj)+1).  Double-buffered LDS, one
//   barrier per 16-h chunk, next chunk's global loads in flight during compute.
__global__ __launch_bounds__(256) void biaffine4(
    const float* __restrict__ hij, const float* __restrict__ va,
    float* __restrict__ partials) {
  __shared__ __align__(16) float his[2][16][34];  // [buf][h][c]
  __shared__ __align__(16) float hjs[2][16][34];  // [buf][h][a]
  __shared__ __align__(16) float vas2[192];
  __shared__ float svas;
  const int z = blockIdx.z;
  const int b = z >> 2;
  const int ch = z & 3;
  const int hc0 = ch * 192;
  const int a0 = blockIdx.y * 32;
  const int c0 = blockIdx.x * 32;
  const int t = threadIdx.x;
  if (t < 192) vas2[t] = -2.f * va[hc0 + t];
  __syncthreads();
  if (t < 64) {
    float s = vas2[t] + vas2[t + 64] + vas2[t + 128];
#pragma unroll
    for (int off = 32; off > 0; off >>= 1) s += __shfl_xor(s, off);
    if (t == 0) svas = -0.5f * s;
  }
  const int lh = t & 15;
  const int lr = t >> 4;
  const int ca = (t & 15) * 2;
  const int aa = (t >> 4) * 2;
  const float* pi0b = hij + (size_t)(b * S + c0 + lr) * 1536 + hc0 + lh;
  const float* pi1b = hij + (size_t)(b * S + c0 + lr + 16) * 1536 + hc0 + lh;
  const float* pj0b = hij + (size_t)(b * S + a0 + lr) * 1536 + 768 + hc0 + lh;
  const float* pj1b = hij + (size_t)(b * S + a0 + lr + 16) * 1536 + 768 + hc0 + lh;
  float acc00 = 0.f, acc01 = 0.f, acc10 = 0.f, acc11 = 0.f;

  float pi0 = pi0b[0], pi1 = pi1b[0], pj0 = pj0b[0], pj1 = pj1b[0];
  for (int hr = 0; hr < 192; hr += 16) {
    const int bf = (hr >> 4) & 1;
    his[bf][lh][lr]      = pi0;
    his[bf][lh][lr + 16] = pi1;
    hjs[bf][lh][lr]      = pj0;
    hjs[bf][lh][lr + 16] = pj1;
    __syncthreads();  // single barrier: buf^1 writers gated 2 iters back
    if (hr + 16 < 192) {
      pi0 = pi0b[hr + 16]; pi1 = pi1b[hr + 16];
      pj0 = pj0b[hr + 16]; pj1 = pj1b[hr + 16];
    }
    float vreg[16];
    *(float4*)&vreg[0]  = *(const float4*)&vas2[hr + 0];
    *(float4*)&vreg[4]  = *(const float4*)&vas2[hr + 4];
    *(float4*)&vreg[8]  = *(const float4*)&vas2[hr + 8];
    *(float4*)&vreg[12] = *(const float4*)&vas2[hr + 12];
#pragma unroll
    for (int h = 0; h < 16; ++h) {
      float v = vreg[h];
      float2 xi = *(const float2*)&his[bf][h][ca];
      float2 xj = *(const float2*)&hjs[bf][h][aa];
      acc00 = fmaf(v, rcp_native(exp2_native(xi.x + xj.x) + 1.f), acc00);
      acc01 = fmaf(v, rcp_native(exp2_native(xi.y + xj.x) + 1.f), acc01);
      acc10 = fmaf(v, rcp_native(exp2_native(xi.x + xj.y) + 1.f), acc10);
      acc11 = fmaf(v, rcp_native(exp2_native(xi.y + xj.y) + 1.f), acc11);
    }
  }
  const float sv = svas;
  float* pout = partials + (size_t)ch * (NB * S * S);
  float2 r0 = {acc00 + sv, acc01 + sv};
  float2 r1 = {acc10 + sv, acc11 + sv};
  *(float2*)&pout[(b * S + a0 + aa) * S + c0 + ca]     = r0;
  *(float2*)&pout[(b * S + a0 + aa + 1) * S + c0 + ca] = r1;
}

// ---------------------------------------------------------------------------
// Stage 3: combine 4 partials -> logits (d_out) + top-4 per row.
__global__ __launch_bounds__(64) void topk_kernel(
    const float* __restrict__ partials, float* __restrict__ logits,
    int* __restrict__ idx) {
  const int row = blockIdx.x;  // b*S + a
  const int lane = threadIdx.x;
  const int P = NB * S * S;
  float v[4];
#pragma unroll
  for (int j = 0; j < 4; ++j) {
    int c = row * S + j * 64 + lane;
    v[j] = ((partials[c] + partials[c + P]) + partials[c + 2 * P]) + partials[c + 3 * P];
    logits[c] = v[j];
  }
#pragma unroll
  for (int k = 0; k < TOPK; ++k) {
    float bestv = v[0];
    int besti = lane;
#pragma unroll
    for (int j = 1; j < 4; ++j) {
      int c = j * 64 + lane;
      if (v[j] > bestv) { bestv = v[j]; besti = c; }
    }
#pragma unroll
    for (int off = 32; off > 0; off >>= 1) {
      float ov = __shfl_xor(bestv, off);
      int oi = __shfl_xor(besti, off);
      if (ov > bestv || (ov == bestv && oi < besti)) { bestv = ov; besti = oi; }
    }
    int mj = besti >> 6, ml = besti & 63;
#pragma unroll
    for (int j = 0; j < 4; ++j)
      if (lane == ml && j == mj) v[j] = -3.402823466e38f;
    if (lane == 0) idx[row * TOPK + k] = besti;
  }
}

// ---------------------------------------------------------------------------
// Stage 4+5 fused: hidden = tanh(cat . dense_w^T + dense_b) computed per
// 64x64 tile (bf16 MFMA, fp32 sources converted in staging); fc partials
// (hidden-tile . fc_w^T) reduced in-block and atomicAdd'ed into out_type
// (zeroed by memset; block n0==0 adds fc_b). No hidden global round-trip.
__global__ __launch_bounds__(256) void dense_mfma_fc(
    const float* __restrict__ pooled, const int* __restrict__ idx,
    const float* __restrict__ dense_w, const float* __restrict__ dense_b,
    const float* __restrict__ fc_w, const float* __restrict__ fc_b,
    float* __restrict__ out_type) {
  __shared__ __align__(16) __bf16 As[64][40];
  __shared__ __align__(16) __bf16 Bs[64][40];
  __shared__ __align__(16) __bf16 hs[64][68];  // hidden tile for fc reduction
  const int m0 = blockIdx.x * 64;
  const int n0 = blockIdx.y * 64;
  const int t = threadIdx.x;
  const int srow = t >> 2;
  const int kq8 = (t & 3) * 8;
  const int r = m0 + srow;
  const int kk = r & 3, s = (r >> 2) & 255, b = r >> 10;
  const float* dep  = pooled + (size_t)(b * S + s) * H;
  const float* head = pooled + (size_t)(b * S + idx[(b * S + s) * TOPK + kk]) * H;
  const float* brow = dense_w + (size_t)(n0 + srow) * (2 * H);
  const int lane = t & 63;
  const int wave = t >> 6;
  const int wm = (wave & 1) * 32;
  const int wn = (wave >> 1) * 32;
  const int fm = lane & 15;
  const int quad = lane >> 4;
  floatx4 acc[2][2] = {};

  for (int kc = 0; kc < 2 * H; kc += 32) {
    const float* ap = (kc < H) ? (dep + kc) : (head + (kc - H));
    {
      float4 a0 = *(const float4*)&ap[kq8];
      float4 a1 = *(const float4*)&ap[kq8 + 4];
      float f[8] = {a0.x, a0.y, a0.z, a0.w, a1.x, a1.y, a1.z, a1.w};
      bf16x8 hv;
#pragma unroll
      for (int k = 0; k < 8; ++k) hv[k] = (__bf16)f[k];
      *(bf16x8*)&As[srow][kq8] = hv;
    }
    {
      float4 w0 = *(const float4*)&brow[kc + kq8];
      float4 w1 = *(const float4*)&brow[kc + kq8 + 4];
      float f[8] = {w0.x, w0.y, w0.z, w0.w, w1.x, w1.y, w1.z, w1.w};
      bf16x8 hv;
#pragma unroll
      for (int k = 0; k < 8; ++k) hv[k] = (__bf16)f[k];
      *(bf16x8*)&Bs[srow][kq8] = hv;
    }
    __syncthreads();
    bf16x8 af[2], bfr[2];
#pragma unroll
    for (int i = 0; i < 2; ++i) {
      af[i]  = *(const bf16x8*)&As[wm + i * 16 + fm][quad * 8];
      bfr[i] = *(const bf16x8*)&Bs[wn + i * 16 + fm][quad * 8];
    }
#pragma unroll
    for (int i = 0; i < 2; ++i)
#pragma unroll
      for (int j = 0; j < 2; ++j)
        acc[i][j] = __builtin_amdgcn_mfma_f32_16x16x32_bf16(af[i], bfr[j], acc[i][j], 0, 0, 0);
    __syncthreads();
  }
  // epilogue: tanh -> bf16 hidden tile in LDS
#pragma unroll
  for (int i = 0; i < 2; ++i)
#pragma unroll
    for (int j = 0; j < 2; ++j) {
      const int col = wn + j * 16 + fm;
      const float bias = dense_b[n0 + col];
#pragma unroll
      for (int rg = 0; rg < 4; ++rg) {
        const int row = wm + i * 16 + quad * 4 + rg;
        hs[row][col] = (__bf16)fast_tanh(acc[i][j][rg] + bias);
      }
    }
  __syncthreads();
  // fc partial: thread t handles row t>>2, 16 cols at (t&3)*16
  const int frow = t >> 2;
  const int q = t & 3;
  float accl[L] = {};
#pragma unroll
  for (int c4 = 0; c4 < 16; c4 += 4) {
    bf16x4 hv = *(const bf16x4*)&hs[frow][q * 16 + c4];
    float x0 = (float)hv[0], x1 = (float)hv[1], x2 = (float)hv[2], x3 = (float)hv[3];
#pragma unroll
    for (int l = 0; l < L; ++l) {
      float4 w = *(const float4*)&fc_w[l * H + n0 + q * 16 + c4];
      accl[l] = fmaf(x0, w.x, accl[l]);
      accl[l] = fmaf(x1, w.y, accl[l]);
      accl[l] = fmaf(x2, w.z, accl[l]);
      accl[l] = fmaf(x3, w.w, accl[l]);
    }
  }
#pragma unroll
  for (int l = 0; l < L; ++l) {
    accl[l] += __shfl_xor(accl[l], 1);
    accl[l] += __shfl_xor(accl[l], 2);
  }
  if (q == 0) {
#pragma unroll
    for (int l = 0; l < L; ++l) {
      float add = accl[l] + ((blockIdx.y == 0) ? fc_b[l] : 0.f);
      atomicAdd(&out_type[(size_t)(m0 + frow) * L + l], add);
    }
  }
}

// ---------------------------------------------------------------------------
extern "C" void kernel_launch(void* const* d_in, const int* in_sizes, int n_in,
                              void* d_out, int out_size, void* d_ws, size_t ws_size,
                              hipStream_t stream) {
  const float* pooled  = (const float*)d_in[0];
  const float* Wa_w    = (const float*)d_in[1];
  const float* Wa_b    = (const float*)d_in[2];
  const float* Ua_w    = (const float*)d_in[3];
  const float* Ua_b    = (const float*)d_in[4];
  const float* va_w    = (const float*)d_in[5];
  const float* dense_w = (const float*)d_in[6];
  const float* dense_b = (const float*)d_in[7];
  const float* fc_w    = (const float*)d_in[8];
  const float* fc_b    = (const float*)d_in[9];

  float* logits   = (float*)d_out;            // (4,256,256)
  float* out_type = logits + NB * S * S;      // (4,256,4,4) = 16384 floats

  // ws: hij [0,6MB) ; partials [6MB,10MB) ; idx
  float* hij      = (float*)d_ws;                      // 1,572,864 f
  float* partials = hij + 1572864;                     // 1,048,576 f
  int*   idxbuf   = (int*)(partials + 1048576);        // 4096 ints

  hipMemsetAsync(out_type, 0, (size_t)NB * S * TOPK * L * sizeof(float), stream);
  proj_mfma<<<dim3(32, 24), 256, 0, stream>>>(pooled, Wa_w, Ua_w, Wa_b, Ua_b, hij);
  biaffine4<<<dim3(8, 8, NB * NH), 256, 0, stream>>>(hij, va_w, partials);
  topk_kernel<<<dim3(1024), 64, 0, stream>>>(partials, logits, idxbuf);
  dense_mfma_fc<<<dim3(64, 12), 256, 0, stream>>>(pooled, idxbuf, dense_w,
                                                  dense_b, fc_w, fc_b, out_type);
}